// Round 4
// baseline (193.427 us; speedup 1.0000x reference)
//
#include <hip/hip_runtime.h>
#include <math.h>

#define T_TGT 50
#define NCLS 80
#define NBATCH 16

// blocks per batch per layer: ceil(3*H*H / 256)
#define NB_L0 5     // 3*19*19 = 1083
#define NB_L1 17    // 3*38*38 = 4332
#define NB_L2 68    // 3*76*76 = 17328
#define NB_MAIN ((NB_L0 + NB_L1 + NB_L2) * NBATCH)   // 1440
#define N_CLS_UNITS (T_TGT * NBATCH * 3)             // 2400
#define NB_CLS ((N_CLS_UNITS + 3) / 4)               // 600 (4 waves/block)
#define NB_TOTAL (NB_MAIN + NB_CLS)                  // 2040

// harness re-poisons d_ws to 0xAA bytes before every launch -> counter's
// initial value is deterministic; no memset node needed.
#define POISON32 0xAAAAAAAAu

__constant__ float c_anchors[18] = {10,13,16,30,33,23,30,61,62,45,
                                    59,119,116,90,156,198,373,326};

__device__ __forceinline__ float softplusf(float x){
    return fmaxf(x, 0.f) + log1pf(expf(-fabsf(x)));
}
__device__ __forceinline__ float bcef(float x, float t){
    return t * softplusf(-x) + (1.f - t) * softplusf(x);
}

struct TgtMeta {
    float4 box;      // tlx, tly, brx, bry
    float2 misc;     // x = 0.7*truth_area, y = key (int bits)
    float fx, fy;    // xy targets (fractional)
    float lw, lh;    // wh targets (log space)
    float w2;        // scale^2 = 2 - area/fs^2
};

// per-cell work for one layer; returns this thread's loss contribution
template<int H, int STRIDE, int GROUP>
__device__ float main_cells(const float* __restrict__ raw,
                            const float* __restrict__ targets,
                            int b, int cb, int tid, TgtMeta* s_t)
{
    constexpr int HH = H * H;
    constexpr int CELLS = 3 * HH;

    if (tid < T_TGT) {
        const float* lab = targets + ((size_t)b * T_TGT + tid) * 5;
        float cf = lab[0], x = lab[1], y = lab[2], w = lab[3], h = lab[4];
        bool valid = (cf + x + y + w + h) > 0.f;
        const float fs = (float)H;
        float tx = x * fs, ty = y * fs, tw = w * fs, th = h * fs;
        int gi = (int)tx, gj = (int)ty;
        float tarea = tw * th;
        float best = -1.f; int bestn = 0;
        #pragma unroll
        for (int n = 0; n < 9; n++) {
            float aw = c_anchors[2*n]   * (1.f / STRIDE);
            float ah = c_anchors[2*n+1] * (1.f / STRIDE);
            float mw = fminf(tw, aw), mh = fminf(th, ah);
            float inter = (mw > 0.f && mh > 0.f) ? mw * mh : 0.f;
            float iou = inter / (tarea + aw * ah - inter);
            if (iou > best) { best = iou; bestn = n; }
        }
        bool sel = valid && ((bestn / 3) == GROUP);
        int bn = bestn % 3;
        int key = sel ? ((bn << 20) | (gj << 10) | gi) : -1;
        s_t[tid].box  = make_float4(tx - tw*0.5f, ty - th*0.5f,
                                    tx + tw*0.5f, ty + th*0.5f);
        s_t[tid].misc = make_float2(0.7f * tarea, __int_as_float(key));
        s_t[tid].w2 = 2.f - tarea / (fs * fs);
        float awm = c_anchors[2*(3*GROUP + bn)]   * (1.f / STRIDE);
        float ahm = c_anchors[2*(3*GROUP + bn)+1] * (1.f / STRIDE);
        s_t[tid].lw = logf(tw / awm + 1e-16f);
        s_t[tid].lh = logf(th / ahm + 1e-16f);
        s_t[tid].fx = tx - (float)gi;
        s_t[tid].fy = ty - (float)gj;
    }
    __syncthreads();

    float local = 0.f;
    const int c = cb * 256 + tid;
    if (c < CELLS) {
        const int a   = c / HH;
        const int rem = c - a * HH;
        const int j   = rem / H;
        const int i   = rem - j * H;
        const float* base = raw + ((size_t)b * 255 + a * 85) * HH + rem;
        float x0 = base[0];
        float x1 = base[HH];
        float x2 = base[2 * HH];
        float x3 = base[3 * HH];
        float x4 = base[4 * HH];

        float s0 = 1.f / (1.f + expf(-x0));
        float s1 = 1.f / (1.f + expf(-x1));
        float manw = c_anchors[2*(3*GROUP + a)]   * (1.f / STRIDE);
        float manh = c_anchors[2*(3*GROUP + a)+1] * (1.f / STRIDE);
        float px = s0 + (float)i, py = s1 + (float)j;
        float pw = expf(x2) * manw, ph = expf(x3) * manh;
        float atlx = px - pw * 0.5f, atly = py - ph * 0.5f;
        float abrx = px + pw * 0.5f, abry = py + ph * 0.5f;
        float carea_a = 0.7f * (pw * ph);
        const int mykey = (a << 20) | (j << 10) | i;

        int winner = -1;
        bool ign = false;
        #pragma unroll 10
        for (int t = 0; t < T_TGT; t++) {
            float4 bx = s_t[t].box;
            float2 mi = s_t[t].misc;
            float tlx = fmaxf(atlx, bx.x);
            float tly = fmaxf(atly, bx.y);
            float brx = fminf(abrx, bx.z);
            float bry = fminf(abry, bx.w);
            float dx = brx - tlx, dy = bry - tly;
            // piou > 0.7  <=>  1.7*ai > 0.7*(area_a + area_b)  (overlap > 0)
            ign = ign || ((dx > 0.f) & (dy > 0.f) &
                          (1.7f * (dx * dy) > carea_a + mi.x));
            if (__float_as_int(mi.y) == mykey) winner = t;  // last-write-wins
        }

        if (winner >= 0) {
            local += softplusf(-x4);               // objectness target = 1
            float w2 = s_t[winner].w2;
            local += w2 * (bcef(x0, s_t[winner].fx) + bcef(x1, s_t[winner].fy));
            float dw = x2 - s_t[winner].lw;
            float dh = x3 - s_t[winner].lh;
            local += 0.5f * w2 * (dw * dw + dh * dh);
        } else if (!ign) {
            local += softplusf(x4);                // objectness target = 0
        }
    }
    return local;
}

// class loss for one (target, batch, layer) unit, handled by one wave
__device__ float class_unit(const float* __restrict__ r0,
                            const float* __restrict__ r1,
                            const float* __restrict__ r2,
                            const float* __restrict__ targets,
                            int u, int lane)
{
    const int L   = u / (T_TGT * NBATCH);
    const int rem = u - L * (T_TGT * NBATCH);
    const int b   = rem / T_TGT;
    const int t0  = rem - b * T_TGT;

    const int Hs[3] = {19, 38, 76};
    const float inv_s[3] = {1.f/32.f, 1.f/16.f, 1.f/8.f};
    const int Gs[3] = {2, 1, 0};
    const float* raw = (L == 0) ? r0 : (L == 1) ? r1 : r2;
    const int H = Hs[L];
    const int HH = H * H;
    const float is = inv_s[L];
    const int group = Gs[L];

    int selkey = 0x40000000 | lane;   // sentinel, never matches a real key
    int clsid = 0;
    if (lane < T_TGT) {
        const float* lab = targets + ((size_t)b * T_TGT + lane) * 5;
        float cf = lab[0], x = lab[1], y = lab[2], w = lab[3], h = lab[4];
        bool valid = (cf + x + y + w + h) > 0.f;
        float fs = (float)H;
        float tx = x * fs, ty = y * fs, tw = w * fs, th = h * fs;
        float tarea = tw * th;
        float best = -1.f; int bestn = 0;
        #pragma unroll
        for (int n = 0; n < 9; n++) {
            float aw = c_anchors[2*n] * is, ah = c_anchors[2*n+1] * is;
            float mw = fminf(tw, aw), mh = fminf(th, ah);
            float inter = (mw > 0.f && mh > 0.f) ? mw * mh : 0.f;
            float iou = inter / (tarea + aw * ah - inter);
            if (iou > best) { best = iou; bestn = n; }
        }
        if (valid && (bestn / 3) == group) {
            int bn = bestn % 3, gi = (int)tx, gj = (int)ty;
            selkey = (bn << 20) | (gj << 10) | gi;
        }
        clsid = (int)cf;
    }

    const int k0 = __shfl(selkey, t0);
    bool active = !(k0 & 0x40000000);                 // t0 selected?
    unsigned long long dup = __ballot(selkey == k0);
    active = active && !(dup >> (t0 + 1));            // later target wins cell

    float local = 0.f;
    if (active) {   // wave-uniform branch
        const int cls0 = __shfl(clsid, t0);
        const int gi = k0 & 1023, gj = (k0 >> 10) & 1023, bn = k0 >> 20;
        const float* base = raw + ((size_t)b * 255 + bn * 85) * HH + gj * H + gi;
        // class loss = sum_c softplus(x_c) - x_cls
        float xc = base[(size_t)(5 + lane) * HH];               // classes 0..63
        local = softplusf(xc) - ((lane == cls0) ? xc : 0.f);
        if (lane < 16) {
            float xh = base[(size_t)(69 + lane) * HH];          // classes 64..79
            local += softplusf(xh) - ((lane + 64 == cls0) ? xh : 0.f);
        }
    }
    return local;
}

__global__ __launch_bounds__(256)
void yolo_fused(const float* __restrict__ r0,
                const float* __restrict__ r1,
                const float* __restrict__ r2,
                const float* __restrict__ targets,
                float* __restrict__ partial,
                unsigned int* __restrict__ counter,
                float* __restrict__ out)
{
    __shared__ TgtMeta s_t[T_TGT];
    __shared__ float s_wsum[4];
    __shared__ bool s_last;

    const int blk = blockIdx.x;
    const int tid = threadIdx.x;
    float local = 0.f;

    if (blk < NB_L0 * NBATCH) {
        int b = blk / NB_L0, cb = blk - b * NB_L0;
        local = main_cells<19, 32, 2>(r0, targets, b, cb, tid, s_t);
    } else if (blk < (NB_L0 + NB_L1) * NBATCH) {
        int q = blk - NB_L0 * NBATCH;
        int b = q / NB_L1, cb = q - b * NB_L1;
        local = main_cells<38, 16, 1>(r1, targets, b, cb, tid, s_t);
    } else if (blk < NB_MAIN) {
        int q = blk - (NB_L0 + NB_L1) * NBATCH;
        int b = q / NB_L2, cb = q - b * NB_L2;
        local = main_cells<76, 8, 0>(r2, targets, b, cb, tid, s_t);
    } else {
        int u = (blk - NB_MAIN) * 4 + (tid >> 6);
        if (u < N_CLS_UNITS)
            local = class_unit(r0, r1, r2, targets, u, tid & 63);
    }

    // block reduction -> unique partial slot
    for (int off = 32; off > 0; off >>= 1)
        local += __shfl_down(local, off, 64);
    const int lane = tid & 63, wv = tid >> 6;
    if (lane == 0) s_wsum[wv] = local;
    __syncthreads();
    if (tid == 0) {
        partial[blk] = s_wsum[0] + s_wsum[1] + s_wsum[2] + s_wsum[3];
        __threadfence();                       // publish partial device-wide
        unsigned int old = atomicAdd(counter, 1u);   // device-scope
        s_last = (old == POISON32 + (unsigned)NB_TOTAL - 1u);
    }
    __syncthreads();

    // the last-finishing block reduces all partials (L2-hot) and writes out
    if (s_last) {
        __threadfence();                       // acquire partials
        float s = 0.f;
        for (int i = tid; i < NB_TOTAL; i += 256) s += partial[i];
        for (int off = 32; off > 0; off >>= 1)
            s += __shfl_down(s, off, 64);
        if (lane == 0) s_wsum[wv] = s;
        __syncthreads();
        if (tid == 0) out[0] = s_wsum[0] + s_wsum[1] + s_wsum[2] + s_wsum[3];
    }
}

extern "C" void kernel_launch(void* const* d_in, const int* in_sizes, int n_in,
                              void* d_out, int out_size, void* d_ws, size_t ws_size,
                              hipStream_t stream)
{
    const float* out0 = (const float*)d_in[0];
    const float* out1 = (const float*)d_in[1];
    const float* out2 = (const float*)d_in[2];
    const float* tgt  = (const float*)d_in[3];
    float* out = (float*)d_out;
    float* partial = (float*)d_ws;                            // NB_TOTAL floats
    unsigned int* counter = (unsigned int*)((char*)d_ws + 16384);

    yolo_fused<<<NB_TOTAL, 256, 0, stream>>>(out0, out1, out2, tgt,
                                             partial, counter, out);
}

// Round 5
// 152.884 us; speedup vs baseline: 1.2652x; 1.2652x over previous
//
#include <hip/hip_runtime.h>
#include <math.h>

#define T_TGT 50
#define NCLS 80
#define NBATCH 16

// blocks per batch per layer: ceil(3*H*H / 256)
#define NB_L0 5     // 3*19*19 = 1083
#define NB_L1 17    // 3*38*38 = 4332
#define NB_L2 68    // 3*76*76 = 17328
#define NB_MAIN ((NB_L0 + NB_L1 + NB_L2) * NBATCH)   // 1440
#define N_CLS_UNITS (T_TGT * NBATCH * 3)             // 2400
#define NB_CLS ((N_CLS_UNITS + 3) / 4)               // 600 (4 waves/block)
#define NB_TOTAL (NB_MAIN + NB_CLS)                  // 2040

// NOTE (R4 post-mortem): do NOT use a per-block device-scope atomic/fence
// finish pattern here — 2040 single-address device atomics + __threadfence
// (L2 writeback on non-coherent XCD L2s) serialize at ~25ns each = +40us.
// Two stream-ordered nodes are cheaper.

__constant__ float c_anchors[18] = {10,13,16,30,33,23,30,61,62,45,
                                    59,119,116,90,156,198,373,326};

__device__ __forceinline__ float softplusf(float x){
    return fmaxf(x, 0.f) + log1pf(expf(-fabsf(x)));
}
__device__ __forceinline__ float bcef(float x, float t){
    return t * softplusf(-x) + (1.f - t) * softplusf(x);
}

struct TgtMeta {
    float4 box;      // tlx, tly, brx, bry
    float2 misc;     // x = 0.7*truth_area, y = key (int bits)
    float fx, fy;    // xy targets (fractional)
    float lw, lh;    // wh targets (log space)
    float w2;        // scale^2 = 2 - area/fs^2
};

// per-cell work for one layer; returns this thread's loss contribution
template<int H, int STRIDE, int GROUP>
__device__ float main_cells(const float* __restrict__ raw,
                            const float* __restrict__ targets,
                            int b, int cb, int tid, TgtMeta* s_t)
{
    constexpr int HH = H * H;
    constexpr int CELLS = 3 * HH;

    // ---- issue the 5 channel loads FIRST so they overlap the target
    //      preprocessing + barrier (compiler won't hoist across s_barrier)
    const int c = cb * 256 + tid;
    const bool cell_ok = (c < CELLS);
    int a = 0, j = 0, i = 0;
    float x0 = 0.f, x1 = 0.f, x2 = 0.f, x3 = 0.f, x4 = 0.f;
    if (cell_ok) {
        a = c / HH;
        const int rem = c - a * HH;
        j = rem / H;
        i = rem - j * H;
        const float* base = raw + ((size_t)b * 255 + a * 85) * HH + rem;
        x0 = base[0];
        x1 = base[HH];
        x2 = base[2 * HH];
        x3 = base[3 * HH];
        x4 = base[4 * HH];
    }

    // ---- per-target metadata (threads 0..49), overlapped with loads above
    if (tid < T_TGT) {
        const float* lab = targets + ((size_t)b * T_TGT + tid) * 5;
        float cf = lab[0], x = lab[1], y = lab[2], w = lab[3], h = lab[4];
        bool valid = (cf + x + y + w + h) > 0.f;
        const float fs = (float)H;
        float tx = x * fs, ty = y * fs, tw = w * fs, th = h * fs;
        int gi = (int)tx, gj = (int)ty;
        float tarea = tw * th;
        float best = -1.f; int bestn = 0;
        #pragma unroll
        for (int n = 0; n < 9; n++) {
            float aw = c_anchors[2*n]   * (1.f / STRIDE);
            float ah = c_anchors[2*n+1] * (1.f / STRIDE);
            float mw = fminf(tw, aw), mh = fminf(th, ah);
            float inter = (mw > 0.f && mh > 0.f) ? mw * mh : 0.f;
            float iou = inter / (tarea + aw * ah - inter);
            if (iou > best) { best = iou; bestn = n; }
        }
        bool sel = valid && ((bestn / 3) == GROUP);
        int bn = bestn % 3;
        int key = sel ? ((bn << 20) | (gj << 10) | gi) : -1;
        s_t[tid].box  = make_float4(tx - tw*0.5f, ty - th*0.5f,
                                    tx + tw*0.5f, ty + th*0.5f);
        s_t[tid].misc = make_float2(0.7f * tarea, __int_as_float(key));
        s_t[tid].w2 = 2.f - tarea / (fs * fs);
        float awm = c_anchors[2*(3*GROUP + bn)]   * (1.f / STRIDE);
        float ahm = c_anchors[2*(3*GROUP + bn)+1] * (1.f / STRIDE);
        s_t[tid].lw = logf(tw / awm + 1e-16f);
        s_t[tid].lh = logf(th / ahm + 1e-16f);
        s_t[tid].fx = tx - (float)gi;
        s_t[tid].fy = ty - (float)gj;
    }
    __syncthreads();

    float local = 0.f;
    if (cell_ok) {
        float s0 = 1.f / (1.f + expf(-x0));
        float s1 = 1.f / (1.f + expf(-x1));
        float manw = c_anchors[2*(3*GROUP + a)]   * (1.f / STRIDE);
        float manh = c_anchors[2*(3*GROUP + a)+1] * (1.f / STRIDE);
        float px = s0 + (float)i, py = s1 + (float)j;
        float pw = expf(x2) * manw, ph = expf(x3) * manh;
        float atlx = px - pw * 0.5f, atly = py - ph * 0.5f;
        float abrx = px + pw * 0.5f, abry = py + ph * 0.5f;
        float carea_a = 0.7f * (pw * ph);
        const int mykey = (a << 20) | (j << 10) | i;

        int winner = -1;
        bool ign = false;
        #pragma unroll 10
        for (int t = 0; t < T_TGT; t++) {
            float4 bx = s_t[t].box;
            float2 mi = s_t[t].misc;
            float tlx = fmaxf(atlx, bx.x);
            float tly = fmaxf(atly, bx.y);
            float brx = fminf(abrx, bx.z);
            float bry = fminf(abry, bx.w);
            float dx = brx - tlx, dy = bry - tly;
            float mn = fminf(dx, dy);
            // piou > 0.7  <=>  1.7*ai - 0.7*area_a > 0.7*area_b  (overlap>0)
            ign = ign || ((mn > 0.f) &
                          (fmaf(1.7f, dx * dy, -carea_a) > mi.x));
            if (__float_as_int(mi.y) == mykey) winner = t;  // last-write-wins
        }

        if (winner >= 0) {
            local += softplusf(-x4);               // objectness target = 1
            float w2 = s_t[winner].w2;
            local += w2 * (bcef(x0, s_t[winner].fx) + bcef(x1, s_t[winner].fy));
            float dw = x2 - s_t[winner].lw;
            float dh = x3 - s_t[winner].lh;
            local += 0.5f * w2 * (dw * dw + dh * dh);
        } else if (!ign) {
            local += softplusf(x4);                // objectness target = 0
        }
    }
    return local;
}

// class loss for one (target, batch, layer) unit, handled by one wave
__device__ float class_unit(const float* __restrict__ r0,
                            const float* __restrict__ r1,
                            const float* __restrict__ r2,
                            const float* __restrict__ targets,
                            int u, int lane)
{
    const int L   = u / (T_TGT * NBATCH);
    const int rem = u - L * (T_TGT * NBATCH);
    const int b   = rem / T_TGT;
    const int t0  = rem - b * T_TGT;

    const int Hs[3] = {19, 38, 76};
    const float inv_s[3] = {1.f/32.f, 1.f/16.f, 1.f/8.f};
    const int Gs[3] = {2, 1, 0};
    const float* raw = (L == 0) ? r0 : (L == 1) ? r1 : r2;
    const int H = Hs[L];
    const int HH = H * H;
    const float is = inv_s[L];
    const int group = Gs[L];

    int selkey = 0x40000000 | lane;   // sentinel, never matches a real key
    int clsid = 0;
    if (lane < T_TGT) {
        const float* lab = targets + ((size_t)b * T_TGT + lane) * 5;
        float cf = lab[0], x = lab[1], y = lab[2], w = lab[3], h = lab[4];
        bool valid = (cf + x + y + w + h) > 0.f;
        float fs = (float)H;
        float tx = x * fs, ty = y * fs, tw = w * fs, th = h * fs;
        float tarea = tw * th;
        float best = -1.f; int bestn = 0;
        #pragma unroll
        for (int n = 0; n < 9; n++) {
            float aw = c_anchors[2*n] * is, ah = c_anchors[2*n+1] * is;
            float mw = fminf(tw, aw), mh = fminf(th, ah);
            float inter = (mw > 0.f && mh > 0.f) ? mw * mh : 0.f;
            float iou = inter / (tarea + aw * ah - inter);
            if (iou > best) { best = iou; bestn = n; }
        }
        if (valid && (bestn / 3) == group) {
            int bn = bestn % 3, gi = (int)tx, gj = (int)ty;
            selkey = (bn << 20) | (gj << 10) | gi;
        }
        clsid = (int)cf;
    }

    const int k0 = __shfl(selkey, t0);
    bool active = !(k0 & 0x40000000);                 // t0 selected?
    unsigned long long dup = __ballot(selkey == k0);
    active = active && !(dup >> (t0 + 1));            // later target wins cell

    float local = 0.f;
    if (active) {   // wave-uniform branch
        const int cls0 = __shfl(clsid, t0);
        const int gi = k0 & 1023, gj = (k0 >> 10) & 1023, bn = k0 >> 20;
        const float* base = raw + ((size_t)b * 255 + bn * 85) * HH + gj * H + gi;
        // class loss = sum_c softplus(x_c) - x_cls
        float xc = base[(size_t)(5 + lane) * HH];               // classes 0..63
        local = softplusf(xc) - ((lane == cls0) ? xc : 0.f);
        if (lane < 16) {
            float xh = base[(size_t)(69 + lane) * HH];          // classes 64..79
            local += softplusf(xh) - ((lane + 64 == cls0) ? xh : 0.f);
        }
    }
    return local;
}

__global__ __launch_bounds__(256)
void yolo_fused(const float* __restrict__ r0,
                const float* __restrict__ r1,
                const float* __restrict__ r2,
                const float* __restrict__ targets,
                float* __restrict__ partial)
{
    __shared__ TgtMeta s_t[T_TGT];
    __shared__ float s_wsum[4];

    const int blk = blockIdx.x;
    const int tid = threadIdx.x;
    float local = 0.f;

    if (blk < NB_L0 * NBATCH) {
        int b = blk / NB_L0, cb = blk - b * NB_L0;
        local = main_cells<19, 32, 2>(r0, targets, b, cb, tid, s_t);
    } else if (blk < (NB_L0 + NB_L1) * NBATCH) {
        int q = blk - NB_L0 * NBATCH;
        int b = q / NB_L1, cb = q - b * NB_L1;
        local = main_cells<38, 16, 1>(r1, targets, b, cb, tid, s_t);
    } else if (blk < NB_MAIN) {
        int q = blk - (NB_L0 + NB_L1) * NBATCH;
        int b = q / NB_L2, cb = q - b * NB_L2;
        local = main_cells<76, 8, 0>(r2, targets, b, cb, tid, s_t);
    } else {
        int u = (blk - NB_MAIN) * 4 + (tid >> 6);
        if (u < N_CLS_UNITS)
            local = class_unit(r0, r1, r2, targets, u, tid & 63);
    }

    // block reduction -> unique partial slot (no global atomics)
    for (int off = 32; off > 0; off >>= 1)
        local += __shfl_down(local, off, 64);
    const int lane = tid & 63, wv = tid >> 6;
    if (lane == 0) s_wsum[wv] = local;
    __syncthreads();
    if (tid == 0)
        partial[blk] = s_wsum[0] + s_wsum[1] + s_wsum[2] + s_wsum[3];
}

__global__ __launch_bounds__(256)
void yolo_reduce(const float4* __restrict__ partial4, float* __restrict__ out)
{
    const int tid = threadIdx.x;
    constexpr int NV = NB_TOTAL / 4;    // 510 float4s (NB_TOTAL % 4 == 0)
    float4 v = partial4[tid];           // tid < 256 < NV
    float s = v.x + v.y + v.z + v.w;
    if (tid + 256 < NV) {
        float4 u = partial4[tid + 256];
        s += u.x + u.y + u.z + u.w;
    }
    for (int off = 32; off > 0; off >>= 1)
        s += __shfl_down(s, off, 64);
    __shared__ float w[4];
    if ((tid & 63) == 0) w[tid >> 6] = s;
    __syncthreads();
    if (tid == 0) out[0] = w[0] + w[1] + w[2] + w[3];
}

extern "C" void kernel_launch(void* const* d_in, const int* in_sizes, int n_in,
                              void* d_out, int out_size, void* d_ws, size_t ws_size,
                              hipStream_t stream)
{
    const float* out0 = (const float*)d_in[0];
    const float* out1 = (const float*)d_in[1];
    const float* out2 = (const float*)d_in[2];
    const float* tgt  = (const float*)d_in[3];
    float* out = (float*)d_out;
    float* partial = (float*)d_ws;   // NB_TOTAL floats, all slots written

    yolo_fused<<<NB_TOTAL, 256, 0, stream>>>(out0, out1, out2, tgt, partial);
    yolo_reduce<<<1, 256, 0, stream>>>((const float4*)partial, out);
}